// Round 14
// baseline (49.793 us; speedup 1.0000x reference)
//
#include <hip/hip_runtime.h>

// BoundaryLoss: B=2, C=3, D=H=W=96.
// Exact EDT via separable min-plus parabola convolution, WINDOWED (+-8 taps).
// K1: per-(hw)-column d-eighth masks -> u8 D-dist^2 field E1[b][c][d][h][w].
// K2 (2-phase): thread owns (h, 4 consecutive w) of one (d, h-strip, b):
//   H phase: running min over 17 GLOBAL u32 rows of E1 (L2/L3-resident,
//     register-only, no LDS, no barrier) -> 3 packed u16x4.
//   one barrier; W phase: shufflevector sliding windows over 5 LDS cells
//   per class -> final dist^2; softmax epilogue in registers -> partial.
// K3: one block sums 1152 partials.

#define NV 884736      // 96^3
#define SLAB 9216      // 96*96
#define NBLK 1152

typedef unsigned short u16x4 __attribute__((ext_vector_type(4)));

__device__ __forceinline__ int imin(int a, int b) { return a < b ? a : b; }

__device__ __forceinline__ u16x4 vmin4(u16x4 a, u16x4 b) {
#if __has_builtin(__builtin_elementwise_min)
    return __builtin_elementwise_min(a, b);
#else
    u16x4 r;
    r[0] = a[0] < b[0] ? a[0] : b[0];
    r[1] = a[1] < b[1] ? a[1] : b[1];
    r[2] = a[2] < b[2] ? a[2] : b[2];
    r[3] = a[3] < b[3] ? a[3] : b[3];
    return r;
#endif
}

__device__ __forceinline__ u16x4 unpack4(unsigned int x) {
    return (u16x4){(unsigned short)(x & 0xFFu), (unsigned short)((x >> 8) & 0xFFu),
                   (unsigned short)((x >> 16) & 0xFFu), (unsigned short)(x >> 24)};
}

#define VC(c) ((u16x4){(unsigned short)(c), (unsigned short)(c), \
                       (unsigned short)(c), (unsigned short)(c)})

// sliding-window 17-tap min over 20 values held in 5 u16x4 cells P0..P4;
// output lane j = min_k ( v[k+j] + (k-8)^2 ),  v[i] = P[i>>2][i&3]
#define WSWEEP(r, P0, P1, P2, P3, P4) do { \
  r = vmin4(P2, VC(999)); \
  r = vmin4(r, __builtin_shufflevector(P0, P1, 0, 1, 2, 3) + VC(64)); \
  r = vmin4(r, __builtin_shufflevector(P0, P1, 1, 2, 3, 4) + VC(49)); \
  r = vmin4(r, __builtin_shufflevector(P0, P1, 2, 3, 4, 5) + VC(36)); \
  r = vmin4(r, __builtin_shufflevector(P0, P1, 3, 4, 5, 6) + VC(25)); \
  r = vmin4(r, __builtin_shufflevector(P1, P2, 0, 1, 2, 3) + VC(16)); \
  r = vmin4(r, __builtin_shufflevector(P1, P2, 1, 2, 3, 4) + VC(9));  \
  r = vmin4(r, __builtin_shufflevector(P1, P2, 2, 3, 4, 5) + VC(4));  \
  r = vmin4(r, __builtin_shufflevector(P1, P2, 3, 4, 5, 6) + VC(1));  \
  r = vmin4(r, __builtin_shufflevector(P2, P3, 1, 2, 3, 4) + VC(1));  \
  r = vmin4(r, __builtin_shufflevector(P2, P3, 2, 3, 4, 5) + VC(4));  \
  r = vmin4(r, __builtin_shufflevector(P2, P3, 3, 4, 5, 6) + VC(9));  \
  r = vmin4(r, __builtin_shufflevector(P3, P4, 0, 1, 2, 3) + VC(16)); \
  r = vmin4(r, __builtin_shufflevector(P3, P4, 1, 2, 3, 4) + VC(25)); \
  r = vmin4(r, __builtin_shufflevector(P3, P4, 2, 3, 4, 5) + VC(36)); \
  r = vmin4(r, __builtin_shufflevector(P3, P4, 3, 4, 5, 6) + VC(49)); \
  r = vmin4(r, P4 + VC(64)); \
} while (0)

// K1: Grid (36 hw-chunks, 8 d-eighths, 2 b), 256 thr. All-u32 mask pipeline.
__global__ __launch_bounds__(256) void k1_ddist(const int* __restrict__ targets,
                                                unsigned char* __restrict__ E1) {
    int hw = blockIdx.x * 256 + threadIdx.x;       // 0..9215
    int q = blockIdx.y, b = blockIdx.z;
    int d0 = 12 * q;
    unsigned int m0 = 0, m1 = 0, m2 = 0;           // bit k <-> gd = d0-8+k
    const int* tp = targets + (size_t)b * NV + hw;
    #pragma unroll
    for (int k = 0; k < 28; ++k) {
        int gd = d0 - 8 + k;
        if ((unsigned)gd < 96u) {                  // uniform branch (SALU)
            int t = tp[(size_t)gd * SLAB];
            m0 |= (unsigned int)(t == 0) << k;
            m1 |= (unsigned int)(t == 1) << k;
            m2 |= (unsigned int)(t == 2) << k;
        }
    }
    size_t eb = ((size_t)(b * 3) * 96 + d0) * SLAB + hw;
    #pragma unroll
    for (int l = 0; l < 12; ++l) {                 // voxel d = d0+l <-> bit l+8
        unsigned int w0 = (m0 >> l) & 0x1FFFFu;
        unsigned int w1 = (m1 >> l) & 0x1FFFFu;
        unsigned int w2 = (m2 >> l) & 0x1FFFFu;
        int r0 = __builtin_ctz((w0 >> 8) | 0x200u);
        int l0 = __builtin_clz((w0 << 23) | 0x4000u);
        int r1 = __builtin_ctz((w1 >> 8) | 0x200u);
        int l1 = __builtin_clz((w1 << 23) | 0x4000u);
        int r2 = __builtin_ctz((w2 >> 8) | 0x200u);
        int l2 = __builtin_clz((w2 << 23) | 0x4000u);
        int d0_ = imin(r0, l0), d1_ = imin(r1, l1), d2_ = imin(r2, l2);
        E1[eb + (size_t)l * SLAB]                        = (unsigned char)(d0_ * d0_);
        E1[eb + (size_t)(96 * SLAB) + (size_t)l * SLAB]  = (unsigned char)(d1_ * d1_);
        E1[eb + (size_t)(192 * SLAB) + (size_t)l * SLAB] = (unsigned char)(d2_ * d2_);
    }
}

// K2: Grid (96 d, 6 s, 2 b), 384 threads. 2-phase register pipeline.
__global__ __launch_bounds__(384) void k2_fused(const unsigned char* __restrict__ E1,
                                                const float* __restrict__ logits,
                                                double* __restrict__ partials) {
    __shared__ u16x4 PW[3][16][30];    // [class][row][2 guard | 24 data | 2 guard | 2 pad]
    __shared__ float wsum[6];
    int d = blockIdx.x, s = blockIdx.y, b = blockIdx.z;
    int tid = threadIdx.x;
    int eh = tid / 24, eq = tid - 24 * eh;         // eh 0..15, eq 0..23
    int h = 16 * s + eh;
    // early logits loads (epilogue-only; latency hides under H phase)
    size_t lb = (size_t)b * 3 * NV + (size_t)d * SLAB + (size_t)h * 96 + 4 * eq;
    float4 L0 = *(const float4*)&logits[lb];
    float4 L1 = *(const float4*)&logits[lb + NV];
    float4 L2 = *(const float4*)&logits[lb + 2 * (size_t)NV];
    const u16x4 G = {127, 127, 127, 127};
    // guard cells: 3c x 16row x 4 = 192
    if (tid < 192) {
        int c = tid / 64, r2 = tid - 64 * c;
        int row = r2 >> 2, g = r2 & 3;
        int col = (g < 2) ? g : 24 + g;            // 0,1,26,27
        PW[c][row][col] = G;
    }
    // ---- H phase: running min over 17 global rows, all in registers ----
    const unsigned int* E132 = (const unsigned int*)E1;
    int ebase = (b * 3 * 96 + d) * 2304 + eq;
    u16x4 H0 = VC(999), H1 = VC(999), H2 = VC(999);
    #pragma unroll
    for (int k = 0; k < 17; ++k) {
        int hg = h - 8 + k;
        int sqc = (k - 8) * (k - 8);
        u16x4 a0 = G, a1 = G, a2 = G;
        if ((unsigned)hg < 96u) {
            int eb = ebase + hg * 24;
            a0 = unpack4(E132[eb]);
            a1 = unpack4(E132[eb + 96 * 2304]);
            a2 = unpack4(E132[eb + 192 * 2304]);
        }
        u16x4 vs = {(unsigned short)sqc, (unsigned short)sqc,
                    (unsigned short)sqc, (unsigned short)sqc};
        H0 = vmin4(H0, a0 + vs);
        H1 = vmin4(H1, a1 + vs);
        H2 = vmin4(H2, a2 + vs);
    }
    PW[0][eh][2 + eq] = H0;
    PW[1][eh][2 + eq] = H1;
    PW[2][eh][2 + eq] = H2;
    __syncthreads();                               // the ONE barrier
    // ---- W phase + epilogue ----
    float acc = 0.0f;
    {
        u16x4 A0 = PW[0][eh][eq], A1 = PW[0][eh][eq + 1], A2 = PW[0][eh][eq + 2],
              A3 = PW[0][eh][eq + 3], A4 = PW[0][eh][eq + 4];
        u16x4 B0 = PW[1][eh][eq], B1 = PW[1][eh][eq + 1], B2 = PW[1][eh][eq + 2],
              B3 = PW[1][eh][eq + 3], B4 = PW[1][eh][eq + 4];
        u16x4 C0 = PW[2][eh][eq], C1 = PW[2][eh][eq + 1], C2 = PW[2][eh][eq + 2],
              C3 = PW[2][eh][eq + 3], C4 = PW[2][eh][eq + 4];
        u16x4 E0v, E1v, E2v;
        WSWEEP(E0v, A0, A1, A2, A3, A4);
        WSWEEP(E1v, B0, B1, B2, B3, B4);
        WSWEEP(E2v, C0, C1, C2, C3, C4);
        #define EPI(J, LA, LB, LC) { \
            int s0 = E0v[J], s1 = E1v[J], s2 = E2v[J]; \
            float x0 = __expf(LA), x1 = __expf(LB), x2 = __expf(LC); \
            float v1 = sqrtf((float)s1) - sqrtf((float)imin(s0, s2)); \
            float v2 = sqrtf((float)s2) - sqrtf((float)imin(s0, s1)); \
            acc += __fdividef(x1 * v1 + x2 * v2, x0 + x1 + x2); }
        EPI(0, L0.x, L1.x, L2.x);
        EPI(1, L0.y, L1.y, L2.y);
        EPI(2, L0.z, L1.z, L2.z);
        EPI(3, L0.w, L1.w, L2.w);
        #undef EPI
    }
    // block reduce (6 waves) -> partial
    #pragma unroll
    for (int off = 32; off > 0; off >>= 1) acc += __shfl_down(acc, off, 64);
    if ((tid & 63) == 0) wsum[tid >> 6] = acc;
    __syncthreads();
    if (tid == 0) {
        int bid = (b * 6 + s) * 96 + d;
        partials[bid] = (double)(wsum[0] + wsum[1] + wsum[2] + wsum[3] + wsum[4] + wsum[5]);
    }
}

// K3: single-block final sum of 1152 partials.
__global__ __launch_bounds__(384) void k3_final(const double* __restrict__ partials,
                                                float* __restrict__ out) {
    __shared__ double dsum[6];
    int tid = threadIdx.x;
    double t = partials[tid] + partials[tid + 384] + partials[tid + 768];
    #pragma unroll
    for (int off = 32; off > 0; off >>= 1) t += __shfl_down(t, off, 64);
    if ((tid & 63) == 0) dsum[tid >> 6] = t;
    __syncthreads();
    if (tid == 0)
        out[0] = (float)((dsum[0] + dsum[1] + dsum[2] + dsum[3] + dsum[4] + dsum[5])
                         / ((double)NV * 2.0));
}

extern "C" void kernel_launch(void* const* d_in, const int* in_sizes, int n_in,
                              void* d_out, int out_size, void* d_ws, size_t ws_size,
                              hipStream_t stream) {
    const float* logits = (const float*)d_in[0];
    const int* targets = (const int*)d_in[1];
    float* out = (float*)d_out;

    double* partials = (double*)d_ws;                          // 1152 doubles
    unsigned char* E1 = (unsigned char*)d_ws + 65536;          // 5.3 MB

    k1_ddist<<<dim3(36, 8, 2), 256, 0, stream>>>(targets, E1);
    k2_fused<<<dim3(96, 6, 2), 384, 0, stream>>>(E1, logits, partials);
    k3_final<<<1, 384, 0, stream>>>(partials, out);
}